// Round 3
// baseline (138.601 us; speedup 1.0000x reference)
//
#include <hip/hip_runtime.h>
#include <hip/hip_bf16.h>
#include <hip/hip_cooperative_groups.h>
#include <math.h>

namespace cg = cooperative_groups;

#define BN 384
#define DD 512
#define LN 40
#define CLOG 144.26950408889634f   // 100 * log2(e)

typedef __attribute__((ext_vector_type(8))) short short8;
typedef __attribute__((ext_vector_type(4))) float f32x4;
typedef unsigned short u16;

static __device__ __forceinline__ short bfbits(float f) {
    __hip_bfloat16 h = __float2bfloat16(f);
    return __builtin_bit_cast(short, h);
}

// ---- single fused cooperative kernel ----
// Phase A: norm rows (384 wave-tasks) + label counts (40) + pfrag build (12)
// Phase B: sim = X X^T split-bf16 MFMA (576 16x16-tile wave-tasks) + meta finalize (1)
// Phase C: main rank accumulation (768 WG-tasks, round-2 validated body)
// Phase D: deterministic final reduce (WG 0)
__global__ __launch_bounds__(256, 3) void k_fused(const float* __restrict__ emb,
                                                  const int* __restrict__ labels,
                                                  float* __restrict__ out,
                                                  void* __restrict__ wsv) {
    u16* xh = (u16*)wsv;                      // 384*512 bf16
    u16* xl = xh + BN * DD;                   // 384*512 bf16
    float* sim = (float*)(xl + BN * DD);      // 384*384 f32
    u16* pfrag = (u16*)(sim + BN * BN);       // 36*64*8 bf16
    float* cnt = (float*)(pfrag + 36 * 64 * 8);
    float* w = cnt + 64;
    float* term0 = w + 64;
    float* partials = term0 + 64;             // 768 f32

    cg::grid_group gg = cg::this_grid();
    int bid = blockIdx.x;
    int tid = threadIdx.x;
    int lane = tid & 63;
    int wv = tid >> 6;
    int nwg = gridDim.x;
    int nwaves = nwg * 4;
    int gw = bid * 4 + wv;

    __shared__ float a_lds[BN];
    __shared__ float F_lds[BN];
    __shared__ float wql[48];
    __shared__ float red[16];
    __shared__ float m_sh;
    __shared__ float wpart[4];

    // ================= Phase A =================
    for (int t = gw; t < 436; t += nwaves) {
        if (t < BN) {
            // normalize row t, write bf16 hi/lo split
            const float* row = emb + (size_t)t * DD;
            f32x4 v0 = *(const f32x4*)(row + lane * 8);
            f32x4 v1 = *(const f32x4*)(row + lane * 8 + 4);
            float ss = 0.f;
#pragma unroll
            for (int e = 0; e < 4; ++e) { ss = fmaf(v0[e], v0[e], ss); ss = fmaf(v1[e], v1[e], ss); }
#pragma unroll
            for (int off = 32; off; off >>= 1) ss += __shfl_xor(ss, off);
            float inv = 1.0f / fmaxf(sqrtf(ss), 1e-12f);
            short8 hv, lv;
#pragma unroll
            for (int e = 0; e < 8; ++e) {
                float v = (e < 4 ? v0[e] : v1[e - 4]) * inv;
                __hip_bfloat16 hb = __float2bfloat16(v);
                float hf = __bfloat162float(hb);
                hv[e] = __builtin_bit_cast(short, hb);
                lv[e] = bfbits(v - hf);
            }
            *(short8*)(xh + (size_t)t * DD + lane * 8) = hv;
            *(short8*)(xl + (size_t)t * DD + lane * 8) = lv;
        } else if (t < 424) {
            // count positives for label l
            int l = t - BN;
            int c = 0;
#pragma unroll
            for (int k = lane; k < BN; k += 64) c += labels[k * LN + l];
#pragma unroll
            for (int off = 32; off; off >>= 1) c += __shfl_xor(c, off);
            if (lane == 0) cnt[l] = (float)c;
        } else {
            // build P_ext fragment block for k-step ks
            int ks = t - 424;
#pragma unroll
            for (int lt = 0; lt < 3; ++lt) {
                int u = (ks * 3 + lt) * 64 + lane;
                int kb = ks * 32 + ((lane >> 4) << 3);
                short8 vals;
#pragma unroll
                for (int e = 0; e < 8; ++e) {
                    int k = kb + e;
                    int l = lt * 16 + (lane & 15);
                    short bv = 0;
                    if (l < LN) bv = labels[k * LN + l] ? (short)0x3F80 : (short)0;
                    else if (l == LN) bv = (short)0x3F80;   // ones column -> rk_all
                    vals[e] = bv;
                }
                *(short8*)(pfrag + (size_t)u * 8) = vals;
            }
        }
    }
    gg.sync();

    // ================= Phase B =================
    for (int t = gw; t < 577; t += nwaves) {
        if (t < 576) {
            // sim 16x16 tile: X = Xh + Xl; keep hh + hl + lh
            int i0 = (t / 24) * 16;
            int j0 = (t % 24) * 16;
            f32x4 acc = (f32x4){0.f, 0.f, 0.f, 0.f};
            int r_i = i0 + (lane & 15);
            int r_j = j0 + (lane & 15);
#pragma unroll
            for (int ks = 0; ks < DD / 32; ++ks) {
                int kb = ks * 32 + ((lane >> 4) << 3);
                short8 ah = *(const short8*)(xh + (size_t)r_i * DD + kb);
                short8 al = *(const short8*)(xl + (size_t)r_i * DD + kb);
                short8 bh = *(const short8*)(xh + (size_t)r_j * DD + kb);
                short8 bl = *(const short8*)(xl + (size_t)r_j * DD + kb);
                acc = __builtin_amdgcn_mfma_f32_16x16x32_bf16(ah, bh, acc, 0, 0, 0);
                acc = __builtin_amdgcn_mfma_f32_16x16x32_bf16(ah, bl, acc, 0, 0, 0);
                acc = __builtin_amdgcn_mfma_f32_16x16x32_bf16(al, bh, acc, 0, 0, 0);
            }
            int rbase = i0 + ((lane >> 4) << 2);
#pragma unroll
            for (int rg = 0; rg < 4; ++rg)
                sim[(size_t)(rbase + rg) * BN + j0 + (lane & 15)] = acc[rg];
        } else {
            // meta finalize: w[l], term0
            float c = (lane < LN) ? cnt[lane] : 0.f;
            bool valid = (lane < LN) && (c > 1.0f);
            unsigned long long bal = __ballot(valid);
            float nv = (float)__popcll(bal);
            float nvm = fmaxf(nv, 1.0f);
            if (lane < 48) w[lane] = valid ? 1.0f / (c * (float)BN * nvm) : 0.0f;
            if (lane == 0) term0[0] = (nv > 0.f) ? 1.0f : 0.0f;
        }
    }
    gg.sync();

    // ================= Phase C =================
    for (int task = bid; task < 2 * BN; task += nwg) {
        int q = task >> 1;
        float mx = -3.0e38f, mn = 3.0e38f;
        for (int i = tid; i < BN; i += 256) {
            float a = sim[(size_t)q * BN + i] * CLOG;
            a_lds[i] = a;
            mx = fmaxf(mx, a); mn = fminf(mn, a);
        }
#pragma unroll
        for (int off = 32; off; off >>= 1) {
            mx = fmaxf(mx, __shfl_xor(mx, off));
            mn = fminf(mn, __shfl_xor(mn, off));
        }
        if (lane == 0) { red[wv] = mx; red[8 + wv] = mn; }
        __syncthreads();
        if (tid == 0) {
            float M = fmaxf(fmaxf(red[0], red[1]), fmaxf(red[2], red[3]));
            float N = fminf(fminf(red[8], red[9]), fminf(red[10], red[11]));
            m_sh = 0.5f * (M + N);
        }
        if (tid < 48) wql[tid] = (tid < LN) ? w[tid] * (float)labels[q * LN + tid] : 0.0f;
        __syncthreads();
        float m = m_sh;
        for (int i = tid; i < BN; i += 256) {
            float d = fminf(fmaxf(m - a_lds[i], -126.f), 126.f);
            F_lds[i] = __builtin_amdgcn_exp2f(d);
        }
        __syncthreads();

        int jbase = (task & 1) * 192 + wv * 48;
        float E[3];
#pragma unroll
        for (int t = 0; t < 3; ++t) {
            float aj = a_lds[jbase + t * 16 + (lane & 15)];
            E[t] = __builtin_amdgcn_exp2f(fminf(fmaxf(aj - m, -126.f), 126.f));
        }

        f32x4 acc[3][3];
#pragma unroll
        for (int t = 0; t < 3; ++t)
#pragma unroll
            for (int lt = 0; lt < 3; ++lt) acc[t][lt] = (f32x4){0.f, 0.f, 0.f, 0.f};

        int kg = (lane >> 4) << 3;
        for (int ks = 0; ks < 12; ++ks) {
            const u16* pb = pfrag + ((size_t)(ks * 3) * 64 + lane) * 8;
            short8 bf0 = *(const short8*)(pb);
            short8 bf1 = *(const short8*)(pb + 64 * 8);
            short8 bf2 = *(const short8*)(pb + 128 * 8);
            f32x4 fa = *(const f32x4*)&F_lds[ks * 32 + kg];
            f32x4 fb = *(const f32x4*)&F_lds[ks * 32 + kg + 4];
#pragma unroll
            for (int t = 0; t < 3; ++t) {
                float e = E[t];
                short8 af;
#pragma unroll
                for (int u = 0; u < 4; ++u) {
                    float p0 = fmaf(e, fa[u], 1.0f);
                    float p1 = fmaf(e, fb[u], 1.0f);
                    af[u] = bfbits(__builtin_amdgcn_rcpf(p0));
                    af[u + 4] = bfbits(__builtin_amdgcn_rcpf(p1));
                }
                acc[t][0] = __builtin_amdgcn_mfma_f32_16x16x32_bf16(af, bf0, acc[t][0], 0, 0, 0);
                acc[t][1] = __builtin_amdgcn_mfma_f32_16x16x32_bf16(af, bf1, acc[t][1], 0, 0, 0);
                acc[t][2] = __builtin_amdgcn_mfma_f32_16x16x32_bf16(af, bf2, acc[t][2], 0, 0, 0);
            }
        }

        float part = 0.f;
#pragma unroll
        for (int t = 0; t < 3; ++t) {
#pragma unroll
            for (int rg = 0; rg < 4; ++rg) {
                int j = jbase + t * 16 + ((lane >> 4) << 2) + rg;
                float av = __shfl(acc[t][2][rg], (lane & 48) | 8);   // l=40 ones column
                float W = __builtin_amdgcn_rcpf(0.5f + av);
                float sv = 0.f;
#pragma unroll
                for (int lt = 0; lt < 3; ++lt) {
                    int l = lt * 16 + (lane & 15);
                    float pj = (l < LN) ? (float)labels[j * LN + l] : 0.f;
                    sv = fmaf(wql[l] * pj, 0.5f + acc[t][lt][rg], sv);
                }
                part = fmaf(W, sv, part);
            }
        }
#pragma unroll
        for (int off = 32; off; off >>= 1) part += __shfl_xor(part, off);
        if (lane == 0) wpart[wv] = part;
        __syncthreads();
        if (tid == 0) partials[task] = (wpart[0] + wpart[1]) + (wpart[2] + wpart[3]);
        __syncthreads();
    }
    gg.sync();

    // ================= Phase D =================
    if (bid == 0) {
        float s = 0.f;
        for (int i = tid; i < 768; i += 256) s += partials[i];
#pragma unroll
        for (int off = 32; off; off >>= 1) s += __shfl_xor(s, off);
        if (lane == 0) red[wv] = s;
        __syncthreads();
        if (tid == 0) out[0] = term0[0] - ((red[0] + red[1]) + (red[2] + red[3]));
    }
}

// ---------------- launch ----------------
extern "C" void kernel_launch(void* const* d_in, const int* in_sizes, int n_in,
                              void* d_out, int out_size, void* d_ws, size_t ws_size,
                              hipStream_t stream) {
    const float* emb = (const float*)d_in[0];
    const int* labels = (const int*)d_in[1];
    float* out = (float*)d_out;
    void* ws = d_ws;

    int maxb = 0;
    hipOccupancyMaxActiveBlocksPerMultiprocessor(&maxb, k_fused, 256, 0);
    if (maxb < 1) maxb = 1;
    long grid = (long)maxb * 256;
    if (grid > 768) grid = 768;

    void* args[] = {(void*)&emb, (void*)&labels, (void*)&out, (void*)&ws};
    hipLaunchCooperativeKernel((const void*)k_fused, dim3((unsigned)grid), dim3(256),
                               args, 0, stream);
}

// Round 9
// 48.632 us; speedup vs baseline: 2.8500x; 2.8500x over previous
//
#include <hip/hip_runtime.h>
#include <hip/hip_bf16.h>
#include <math.h>

// Rounds 4-8 failed with ENOSPC in the harness container (round 8: even the
// test-file push failed, before compilation). Environmental; resubmitting the
// round-7 small-artifact 2-dispatch design verbatim.

#define BN 384
#define DD 512
#define LN 40
#define CLOG 144.26950408889634f   // 100 * log2(e)

typedef __attribute__((ext_vector_type(8))) short short8;
typedef __attribute__((ext_vector_type(4))) float f32x4;
typedef unsigned short u16;

// ws layout (bytes)
#define WS_SIM    0           // 384*384*4 = 589824
#define WS_PFRAG  589824      // 36*64*8*2 = 36864
#define WS_CNT    626688      // 64 f32
#define WS_CTR    626944      // uint counter (+pad)
#define WS_PART   627008      // 768 f32   (total 630080)

static __device__ __forceinline__ short bfbits(float f) {
    __hip_bfloat16 h = __float2bfloat16(f);
    return __builtin_bit_cast(short, h);
}

// ---------------- Kernel A: prep (all wave-tasks independent) ----------------
__global__ __launch_bounds__(256) void k_prep(const float* __restrict__ emb,
                                              const int* __restrict__ labels,
                                              char* __restrict__ ws) {
    float* sim = (float*)(ws + WS_SIM);
    u16* pfrag = (u16*)(ws + WS_PFRAG);
    float* cnt = (float*)(ws + WS_CNT);
    unsigned* ctr = (unsigned*)(ws + WS_CTR);
    int lane = threadIdx.x & 63;
    int gw = blockIdx.x * 4 + (threadIdx.x >> 6);

    if (gw < 576) {
        int i0 = (gw / 24) * 16, j0 = (gw % 24) * 16;
        const float* Ar = emb + (size_t)(i0 + (lane & 15)) * DD;
        const float* Br = emb + (size_t)(j0 + (lane & 15)) * DD;
        int kg = (lane >> 4) << 3;
        float ssA = 0.f, ssB = 0.f;
#pragma unroll 1
        for (int ks = 0; ks < 16; ++ks) {
            int kb = ks * 32 + kg;
            f32x4 a0 = *(const f32x4*)(Ar + kb);
            f32x4 a1 = *(const f32x4*)(Ar + kb + 4);
            f32x4 b0 = *(const f32x4*)(Br + kb);
            f32x4 b1 = *(const f32x4*)(Br + kb + 4);
#pragma unroll
            for (int e = 0; e < 4; ++e) {
                ssA = fmaf(a0[e], a0[e], ssA); ssA = fmaf(a1[e], a1[e], ssA);
                ssB = fmaf(b0[e], b0[e], ssB); ssB = fmaf(b1[e], b1[e], ssB);
            }
        }
        ssA += __shfl_xor(ssA, 16); ssA += __shfl_xor(ssA, 32);
        ssB += __shfl_xor(ssB, 16); ssB += __shfl_xor(ssB, 32);
        float invA = 1.0f / fmaxf(sqrtf(ssA), 1e-12f);
        float invB = 1.0f / fmaxf(sqrtf(ssB), 1e-12f);
        f32x4 acc = (f32x4){0.f, 0.f, 0.f, 0.f};
#pragma unroll 1
        for (int ks = 0; ks < 16; ++ks) {
            int kb = ks * 32 + kg;
            f32x4 a0 = *(const f32x4*)(Ar + kb);
            f32x4 a1 = *(const f32x4*)(Ar + kb + 4);
            f32x4 b0 = *(const f32x4*)(Br + kb);
            f32x4 b1 = *(const f32x4*)(Br + kb + 4);
            short8 ah, al, bh, bl;
#pragma unroll
            for (int e = 0; e < 8; ++e) {
                float va = (e < 4 ? a0[e] : a1[e - 4]) * invA;
                __hip_bfloat16 hba = __float2bfloat16(va);
                ah[e] = __builtin_bit_cast(short, hba);
                al[e] = bfbits(va - __bfloat162float(hba));
                float vb = (e < 4 ? b0[e] : b1[e - 4]) * invB;
                __hip_bfloat16 hbb = __float2bfloat16(vb);
                bh[e] = __builtin_bit_cast(short, hbb);
                bl[e] = bfbits(vb - __bfloat162float(hbb));
            }
            acc = __builtin_amdgcn_mfma_f32_16x16x32_bf16(ah, bh, acc, 0, 0, 0);
            acc = __builtin_amdgcn_mfma_f32_16x16x32_bf16(ah, bl, acc, 0, 0, 0);
            acc = __builtin_amdgcn_mfma_f32_16x16x32_bf16(al, bh, acc, 0, 0, 0);
        }
        int rbase = i0 + ((lane >> 4) << 2);
#pragma unroll
        for (int rg = 0; rg < 4; ++rg)
            sim[(size_t)(rbase + rg) * BN + j0 + (lane & 15)] = acc[rg];
    } else if (gw < 616) {
        int l = gw - 576;
        int c = 0;
#pragma unroll 1
        for (int k = lane; k < BN; k += 64) c += labels[k * LN + l];
#pragma unroll
        for (int off = 32; off; off >>= 1) c += __shfl_xor(c, off);
        if (lane == 0) cnt[l] = (float)c;
    } else if (gw < 652) {
        int u = gw - 616;          // (ks*3 + lt)
        int ks = u / 3, lt = u % 3;
        int kb = ks * 32 + ((lane >> 4) << 3);
        short8 vals;
#pragma unroll
        for (int e = 0; e < 8; ++e) {
            int k = kb + e;
            int l = lt * 16 + (lane & 15);
            short bv = 0;
            if (l < LN) bv = labels[k * LN + l] ? (short)0x3F80 : (short)0;
            else if (l == LN) bv = (short)0x3F80;   // ones column -> rk_all
            vals[e] = bv;
        }
        *(short8*)(pfrag + ((size_t)u * 64 + lane) * 8) = vals;
    } else if (gw == 652) {
        if (lane == 0)
            __hip_atomic_store(ctr, 0u, __ATOMIC_RELAXED, __HIP_MEMORY_SCOPE_AGENT);
    }
}

// ---------------- Kernel B: rank accumulation + fused final reduce ----------------
__global__ __launch_bounds__(256) void k_rank(const int* __restrict__ labels,
                                              char* __restrict__ ws,
                                              float* __restrict__ out) {
    float* sim = (float*)(ws + WS_SIM);
    const u16* pfrag = (const u16*)(ws + WS_PFRAG);
    float* cnt = (float*)(ws + WS_CNT);
    unsigned* ctr = (unsigned*)(ws + WS_CTR);
    float* partials = (float*)(ws + WS_PART);

    __shared__ float a_lds[BN];
    __shared__ float F_lds[BN];
    __shared__ float wsh[48];
    __shared__ float wql[48];
    __shared__ float red[16];
    __shared__ float m_sh;
    __shared__ float wpart[4];
    __shared__ float term0_s;
    __shared__ int last_s;

    int tid = threadIdx.x;
    int lane = tid & 63;
    int wv = tid >> 6;
    int task = blockIdx.x;
    int q = task >> 1;

    float mx = -3.0e38f, mn = 3.0e38f;
#pragma unroll 1
    for (int i = tid; i < BN; i += 256) {
        float a = sim[(size_t)q * BN + i] * CLOG;
        a_lds[i] = a;
        mx = fmaxf(mx, a); mn = fminf(mn, a);
    }
#pragma unroll
    for (int off = 32; off; off >>= 1) {
        mx = fmaxf(mx, __shfl_xor(mx, off));
        mn = fminf(mn, __shfl_xor(mn, off));
    }
    if (lane == 0) { red[wv] = mx; red[8 + wv] = mn; }
    if (wv == 0) {
        float c = (lane < LN) ? cnt[lane] : 0.f;
        bool valid = (lane < LN) && (c > 1.0f);
        unsigned long long bal = __ballot(valid);
        float nv = (float)__popcll(bal);
        float nvm = fmaxf(nv, 1.0f);
        if (lane < 48) wsh[lane] = valid ? 1.0f / (c * (float)BN * nvm) : 0.0f;
        if (lane == 0) term0_s = (nv > 0.f) ? 1.0f : 0.0f;
    }
    __syncthreads();
    if (tid == 0) {
        float M = fmaxf(fmaxf(red[0], red[1]), fmaxf(red[2], red[3]));
        float N = fminf(fminf(red[8], red[9]), fminf(red[10], red[11]));
        m_sh = 0.5f * (M + N);
    }
    if (tid < 48) wql[tid] = (tid < LN) ? wsh[tid] * (float)labels[q * LN + tid] : 0.0f;
    __syncthreads();
    float m = m_sh;
#pragma unroll 1
    for (int i = tid; i < BN; i += 256) {
        float d = fminf(fmaxf(m - a_lds[i], -126.f), 126.f);
        F_lds[i] = __builtin_amdgcn_exp2f(d);
    }
    __syncthreads();

    int jbase = (task & 1) * 192 + wv * 48;
    float E[3];
#pragma unroll
    for (int t = 0; t < 3; ++t) {
        float aj = a_lds[jbase + t * 16 + (lane & 15)];
        E[t] = __builtin_amdgcn_exp2f(fminf(fmaxf(aj - m, -126.f), 126.f));
    }

    f32x4 acc[3][3];
#pragma unroll
    for (int t = 0; t < 3; ++t)
#pragma unroll
        for (int lt = 0; lt < 3; ++lt) acc[t][lt] = (f32x4){0.f, 0.f, 0.f, 0.f};

    int kg = (lane >> 4) << 3;
#pragma unroll 1
    for (int ks = 0; ks < 12; ++ks) {
        const u16* pb = pfrag + ((size_t)(ks * 3) * 64 + lane) * 8;
        short8 bf0 = *(const short8*)(pb);
        short8 bf1 = *(const short8*)(pb + 64 * 8);
        short8 bf2 = *(const short8*)(pb + 128 * 8);
        f32x4 fa = *(const f32x4*)&F_lds[ks * 32 + kg];
        f32x4 fb = *(const f32x4*)&F_lds[ks * 32 + kg + 4];
#pragma unroll
        for (int t = 0; t < 3; ++t) {
            float e = E[t];
            short8 af;
#pragma unroll
            for (int u = 0; u < 4; ++u) {
                float p0 = fmaf(e, fa[u], 1.0f);
                float p1 = fmaf(e, fb[u], 1.0f);
                af[u] = bfbits(__builtin_amdgcn_rcpf(p0));
                af[u + 4] = bfbits(__builtin_amdgcn_rcpf(p1));
            }
            acc[t][0] = __builtin_amdgcn_mfma_f32_16x16x32_bf16(af, bf0, acc[t][0], 0, 0, 0);
            acc[t][1] = __builtin_amdgcn_mfma_f32_16x16x32_bf16(af, bf1, acc[t][1], 0, 0, 0);
            acc[t][2] = __builtin_amdgcn_mfma_f32_16x16x32_bf16(af, bf2, acc[t][2], 0, 0, 0);
        }
    }

    float part = 0.f;
#pragma unroll
    for (int t = 0; t < 3; ++t) {
#pragma unroll
        for (int rg = 0; rg < 4; ++rg) {
            int j = jbase + t * 16 + ((lane >> 4) << 2) + rg;
            float av = __shfl(acc[t][2][rg], (lane & 48) | 8);   // l=40 ones column
            float W = __builtin_amdgcn_rcpf(0.5f + av);
            float sv = 0.f;
#pragma unroll
            for (int lt = 0; lt < 3; ++lt) {
                int l = lt * 16 + (lane & 15);
                float pj = (l < LN) ? (float)labels[j * LN + l] : 0.f;
                sv = fmaf(wql[l] * pj, 0.5f + acc[t][lt][rg], sv);
            }
            part = fmaf(W, sv, part);
        }
    }
#pragma unroll
    for (int off = 32; off; off >>= 1) part += __shfl_xor(part, off);
    if (lane == 0) wpart[wv] = part;
    __syncthreads();

    if (tid == 0) {
        float val = (wpart[0] + wpart[1]) + (wpart[2] + wpart[3]);
        __hip_atomic_store(&partials[task], val, __ATOMIC_RELAXED, __HIP_MEMORY_SCOPE_AGENT);
        unsigned old = __hip_atomic_fetch_add(ctr, 1u, __ATOMIC_ACQ_REL, __HIP_MEMORY_SCOPE_AGENT);
        last_s = (old == 2 * BN - 1) ? 1 : 0;
    }
    __syncthreads();
    if (last_s) {
        float s = 0.f;
#pragma unroll 1
        for (int i = tid; i < 2 * BN; i += 256)
            s += __hip_atomic_load(&partials[i], __ATOMIC_RELAXED, __HIP_MEMORY_SCOPE_AGENT);
#pragma unroll
        for (int off = 32; off; off >>= 1) s += __shfl_xor(s, off);
        if (lane == 0) red[wv] = s;
        __syncthreads();
        if (tid == 0) out[0] = term0_s - ((red[0] + red[1]) + (red[2] + red[3]));
    }
}

// ---------------- launch ----------------
extern "C" void kernel_launch(void* const* d_in, const int* in_sizes, int n_in,
                              void* d_out, int out_size, void* d_ws, size_t ws_size,
                              hipStream_t stream) {
    const float* emb = (const float*)d_in[0];
    const int* labels = (const int*)d_in[1];
    float* out = (float*)d_out;
    char* ws = (char*)d_ws;

    k_prep<<<dim3(164), dim3(256), 0, stream>>>(emb, labels, ws);
    k_rank<<<dim3(2 * BN), dim3(256), 0, stream>>>(labels, ws, out);
}